// Round 9
// baseline (10370.175 us; speedup 1.0000x reference)
//
#include <hip/hip_runtime.h>
#include <stdint.h>

#define BB 384
#define LSEQ 64
#define HH 300
#define TDIM 64
#define TT 126
#define NP 63          // pairs
#define KP 320         // padded K per 300-part
#define G4 256
#define G5 1500
#define SEQB 38400     // LSEQ*2*HH
#define NBLK 216       // persistent grid size (must all be co-resident)

typedef unsigned int u32;
typedef unsigned short ush;
typedef float f32x4 __attribute__((ext_vector_type(4)));
typedef short bf16x8 __attribute__((ext_vector_type(8)));

__device__ __forceinline__ float sigm(float x){ return 1.0f/(1.0f + expf(-x)); }
__device__ __forceinline__ ush f2bf(float x){ u32 u = __float_as_uint(x); u32 r = u + 0x7fff + ((u>>16)&1); return (ush)(r>>16); }
__device__ __forceinline__ float bf2f(ush h){ return __uint_as_float(((u32)h)<<16); }
__device__ __forceinline__ bf16x8 ld16(const ush* p){ return *reinterpret_cast<const bf16x8*>(p); }
__device__ __forceinline__ void mfma16(f32x4& d, bf16x8 a, bf16x8 b){
    d = __builtin_amdgcn_mfma_f32_16x16x32_bf16(a, b, d, 0, 0, 0);
}

// hand-rolled grid barrier: monotonic counter, all NBLK blocks co-resident.
// release fence + device-scope atomic arrive; acquire spin; acquire fence.
__device__ __forceinline__ void gbar(int* cnt, int target) {
    __syncthreads();
    if (threadIdx.x == 0) {
        __threadfence();   // writeback my XCD L2 (release)
        __hip_atomic_fetch_add(cnt, 1, __ATOMIC_RELEASE, __HIP_MEMORY_SCOPE_AGENT);
        while (__hip_atomic_load(cnt, __ATOMIC_ACQUIRE, __HIP_MEMORY_SCOPE_AGENT) < target)
            __builtin_amdgcn_s_sleep(2);
        __threadfence();   // invalidate stale L1/L2 lines (acquire)
    }
    __syncthreads();
}

// ---------------- weight prep: bf16 hi/lo planes, K padded 300->320 ----------------
__global__ void k_wprep(const float* __restrict__ Uh, const float* __restrict__ Ul,
                        const float* __restrict__ Ur, const float* __restrict__ Wih,
                        const float* __restrict__ Whh,
                        const float* __restrict__ bih, const float* __restrict__ bhh,
                        ush* ULh, ush* ULl, ush* URh, ush* URl,
                        ush* WihH, ush* WihL, ush* WhhH, ush* WhhL, float* bsum)
{
    int i0 = blockIdx.x*blockDim.x + threadIdx.x;
    int stride = gridDim.x*blockDim.x;
    for (int i = i0; i < G5*KP; i += stride) {
        int j = i / KP, k = i - j*KP;
        float vl = 0.f, vr = 0.f;
        if (k < HH) { float u = Uh[j*HH+k]; vl = u + Ul[j*HH+k]; vr = u + Ur[j*HH+k]; }
        ush h;
        h = f2bf(vl); ULh[i] = h; ULl[i] = f2bf(vl - bf2f(h));
        h = f2bf(vr); URh[i] = h; URl[i] = f2bf(vr - bf2f(h));
    }
    for (int i = i0; i < G4*3*KP; i += stride) {
        int j = i / (3*KP), kk = i - j*(3*KP);
        int part = kk / KP, k = kk - part*KP;
        float v = (k < HH) ? Wih[j*900 + part*HH + k] : 0.f;
        ush h = f2bf(v); WihH[i] = h; WihL[i] = f2bf(v - bf2f(h));
    }
    for (int i = i0; i < G4*TDIM; i += stride) {
        float v = Whh[i]; ush h = f2bf(v); WhhH[i] = h; WhhL[i] = f2bf(v - bf2f(h));
    }
    for (int i = i0; i < G4; i += stride) bsum[i] = bih[i] + bhh[i];
}

// ---------------- token h-part -> bf16 hi/lo, [b*64+t][320] ----------------
__global__ void k_cvt(const float* __restrict__ seq, ush* tokH, ush* tokL)
{
    int i0 = blockIdx.x*blockDim.x + threadIdx.x;
    int stride = gridDim.x*blockDim.x;
    for (int i = i0; i < BB*LSEQ*KP; i += stride) {
        int bt = i / KP, k = i - bt*KP;
        int b = bt >> 6, t = bt & 63;
        float v = (k < HH) ? seq[b*SEQB + t*600 + k] : 0.f;
        ush h = f2bf(v); tokH[i] = h; tokL[i] = f2bf(v - bf2f(h));
    }
}

// ---------------- init state ----------------
__global__ void k_init(const float* __restrict__ seq, const float* __restrict__ th0,
                       const float* __restrict__ tc0, const ush* __restrict__ tokH,
                       const ush* __restrict__ tokL,
                       ush* accH, ush* accL, float* acc_c, float* acc_h,
                       ush* thH, ush* thL, float* tc_buf)
{
    int i0 = blockIdx.x*blockDim.x + threadIdx.x;
    int stride = gridDim.x*blockDim.x;
    for (int i = i0; i < BB*KP; i += stride) {          // acc = token0
        int b = i / KP, k = i - b*KP;
        accH[i] = tokH[b*LSEQ*KP + k]; accL[i] = tokL[b*LSEQ*KP + k];
    }
    for (int i = i0; i < BB*HH; i += stride) {
        int b = i / HH, c = i - b*HH;
        acc_c[i] = seq[b*SEQB + HH + c];
        acc_h[i] = seq[b*SEQB + c];
    }
    for (int i = i0; i < BB*TDIM; i += stride) {
        float v = th0[i]; ush h = f2bf(v);
        thH[i] = h; thL[i] = f2bf(v - bf2f(h));
        tc_buf[i] = tc0[i];
    }
}

// ---------------- per-pair left/right permutation (+ zero barrier counter) ----------------
__global__ __launch_bounds__(448) void k_prep2(const int* __restrict__ trans, int* perm, int* rbarr,
                                               int* bar)
{
    int p = blockIdx.x, t = threadIdx.x;
    if (p == 0 && t == 0) *bar = 0;
    __shared__ int cl, cr, rb;
    if (t == 0) { cl = 0; cr = 0; }
    __syncthreads();
    int isleft = 0;
    if (t < BB) {
        isleft = (trans[t*TT + 2*p + 1] == 2);
        if (isleft) atomicAdd(&cl, 1); else atomicAdd(&cr, 1);
    }
    __syncthreads();
    if (t == 0) { rb = ((cl + 63) >> 6) << 6; rbarr[p] = rb; cl = 0; cr = 0; }
    __syncthreads();
    perm[p*448 + t] = -1;
    __syncthreads();
    if (t < BB) {
        int slot = isleft ? atomicAdd(&cl, 1) : rb + atomicAdd(&cr, 1);
        perm[p*448 + slot] = t;
    }
}

// ---------------- persistent kernel: all 63 pairs, hand-rolled grid barrier ----------------
struct Prm {
    const float* seq; const int* trans;
    const float* Wc; const float* Uhb; const float* bsum;
    const ush* tokH; const ush* tokL;
    ush* accH; ush* accL;
    ush* thH; ush* thL;
    float* tcb; float* acc_c; float* acc_h;
    const ush* ULh; const ush* ULl; const ush* URh; const ush* URl;
    const ush* WihH; const ush* WihL; const ush* WhhH; const ush* WhhL;
    const float* Whh;
    const int* perm; const int* rbarr;
    float* gbufE; float* gbufO; float* Pbuf;
    int* bar;
};

__global__ __launch_bounds__(256) void k_persist(Prm pr)
{
    const int bid = blockIdx.x, tid = threadIdx.x;
    const int w = tid >> 6, lane = tid & 63;
    const int l15 = lane & 15, kg = lane >> 4;

    __shared__ __align__(16) float thl[4][64], tcl[4][64], gel[4][256];
    __shared__ __align__(16) float g5l[4][G5];

    int btgt = 0;
    for (int p = 0; p < NP; ++p) {
        // ================= A phase: MFMA GEMMs =================
        if (bid < 48) {
            // GA_even / GA_odd tiles (fixed block->tile mapping for L2 weight residency)
            const int seg = (bid >= 24);
            const int q = bid - seg*24;
            const int rt = q >> 2, ct = q & 3;
            const int r0 = rt*64, c0 = ct*64;
            const int b = r0 + w*16 + l15;
            f32x4 acc[4];
            #pragma unroll
            for (int cf = 0; cf < 4; ++cf) acc[cf] = (f32x4){0.f,0.f,0.f,0.f};
            const ush* aH[3]; const ush* aL[3];
            if (!seg) {
                aH[0] = pr.tokH + (b*64 + p)*KP;   aL[0] = pr.tokL + (b*64 + p)*KP;
                aH[1] = pr.accH + b*KP;            aL[1] = pr.accL + b*KP;
                aH[2] = pr.tokH + (b*64)*KP;       aL[2] = pr.tokL + (b*64)*KP;
            } else {
                aH[0] = pr.tokH + (b*64 + p+1)*KP; aL[0] = pr.tokL + (b*64 + p+1)*KP;
                aH[1] = pr.tokH + (b*64 + p)*KP;   aL[1] = pr.tokL + (b*64 + p)*KP;
                aH[2] = pr.accH + b*KP;            aL[2] = pr.accL + b*KP;
            }
            const ush* bH[4]; const ush* bL[4];
            #pragma unroll
            for (int cf = 0; cf < 4; ++cf) {
                int j = c0 + cf*16 + l15;
                bH[cf] = pr.WihH + j*(3*KP) + kg*8;
                bL[cf] = pr.WihL + j*(3*KP) + kg*8;
            }
            #pragma unroll
            for (int part = 0; part < 3; ++part) {
                const ush* pah = aH[part] + kg*8;
                const ush* pal = aL[part] + kg*8;
                const int ko = part*KP;
                #pragma unroll
                for (int kc = 0; kc < KP; kc += 32) {
                    bf16x8 ah = ld16(pah + kc);
                    bf16x8 al = ld16(pal + kc);
                    bf16x8 b0 = ld16(bH[0]+ko+kc), b1 = ld16(bH[1]+ko+kc), b2 = ld16(bH[2]+ko+kc), b3 = ld16(bH[3]+ko+kc);
                    bf16x8 c0v = ld16(bL[0]+ko+kc), c1 = ld16(bL[1]+ko+kc), c2 = ld16(bL[2]+ko+kc), c3 = ld16(bL[3]+ko+kc);
                    mfma16(acc[0],ah,b0); mfma16(acc[1],ah,b1); mfma16(acc[2],ah,b2); mfma16(acc[3],ah,b3);
                    mfma16(acc[0],al,b0); mfma16(acc[1],al,b1); mfma16(acc[2],al,b2); mfma16(acc[3],al,b3);
                    mfma16(acc[0],ah,c0v); mfma16(acc[1],ah,c1); mfma16(acc[2],ah,c2); mfma16(acc[3],ah,c3);
                }
            }
            if (!seg) {  // + th_prev @ Whh^T, K=64
                const ush* pah = pr.thH + b*TDIM + kg*8;
                const ush* pal = pr.thL + b*TDIM + kg*8;
                #pragma unroll
                for (int kc = 0; kc < 64; kc += 32) {
                    bf16x8 ah = ld16(pah + kc);
                    bf16x8 al = ld16(pal + kc);
                    #pragma unroll
                    for (int cf = 0; cf < 4; ++cf) {
                        int j = c0 + cf*16 + l15;
                        bf16x8 bh = ld16(pr.WhhH + j*TDIM + kg*8 + kc);
                        bf16x8 bl = ld16(pr.WhhL + j*TDIM + kg*8 + kc);
                        mfma16(acc[cf], ah, bh);
                        mfma16(acc[cf], al, bh);
                        mfma16(acc[cf], ah, bl);
                    }
                }
            }
            float* out = seg ? pr.gbufO : pr.gbufE;
            #pragma unroll
            for (int r = 0; r < 4; ++r) {
                int row = r0 + w*16 + kg*4 + r;
                #pragma unroll
                for (int cf = 0; cf < 4; ++cf) {
                    int col = c0 + cf*16 + l15;
                    out[row*G4 + col] = acc[cf][r];
                }
            }
        } else {
            // P tiles (bid 48..215)
            const int q = bid - 48;
            const int rt = q / 24, ct = q - rt*24;
            const int s0 = rt*64, c0 = ct*64;
            const int* pp = pr.perm + p*448;
            if (pp[s0] >= 0) {
                const int RB = pr.rbarr[p];
                const bool left = (s0 < RB);
                f32x4 acc[4];
                #pragma unroll
                for (int cf = 0; cf < 4; ++cf) acc[cf] = (f32x4){0.f,0.f,0.f,0.f};
                int ar = pp[s0 + w*16 + l15]; if (ar < 0) ar = 0;
                const ush* pah = (left ? pr.tokH + (ar*64 + p)*KP : pr.accH + ar*KP) + kg*8;
                const ush* pal = (left ? pr.tokL + (ar*64 + p)*KP : pr.accL + ar*KP) + kg*8;
                const ush* WBh = left ? pr.ULh : pr.URh;
                const ush* WBl = left ? pr.ULl : pr.URl;
                const ush* bH[4]; const ush* bL[4];
                #pragma unroll
                for (int cf = 0; cf < 4; ++cf) {
                    int j = c0 + cf*16 + l15; if (j > G5-1) j = G5-1;
                    bH[cf] = WBh + j*KP + kg*8;
                    bL[cf] = WBl + j*KP + kg*8;
                }
                #pragma unroll
                for (int kc = 0; kc < KP; kc += 32) {
                    bf16x8 ah = ld16(pah + kc);
                    bf16x8 al = ld16(pal + kc);
                    bf16x8 b0 = ld16(bH[0]+kc), b1 = ld16(bH[1]+kc), b2 = ld16(bH[2]+kc), b3 = ld16(bH[3]+kc);
                    bf16x8 c0v = ld16(bL[0]+kc), c1 = ld16(bL[1]+kc), c2 = ld16(bL[2]+kc), c3 = ld16(bL[3]+kc);
                    mfma16(acc[0],ah,b0); mfma16(acc[1],ah,b1); mfma16(acc[2],ah,b2); mfma16(acc[3],ah,b3);
                    mfma16(acc[0],al,b0); mfma16(acc[1],al,b1); mfma16(acc[2],al,b2); mfma16(acc[3],al,b3);
                    mfma16(acc[0],ah,c0v); mfma16(acc[1],ah,c1); mfma16(acc[2],ah,c2); mfma16(acc[3],ah,c3);
                }
                #pragma unroll
                for (int r = 0; r < 4; ++r) {
                    int prw = pp[s0 + w*16 + kg*4 + r];
                    if (prw < 0) continue;
                    #pragma unroll
                    for (int cf = 0; cf < 4; ++cf) {
                        int col = c0 + cf*16 + l15;
                        if (col < G5) pr.Pbuf[prw*G5 + col] = acc[cf][r];
                    }
                }
            }
        }
        btgt += NBLK;
        gbar(pr.bar, btgt);

        // ================= B phase: sequential core =================
        if (bid < 96) {
            const int r0 = bid*4;
            const int row = tid >> 6, d = tid & 63;
            const int b = r0 + row;
            // tracking LSTM even
            {
                float gi = pr.gbufE[b*G4 + d]        + pr.bsum[d];
                float gf = pr.gbufE[b*G4 + 64 + d]   + pr.bsum[64 + d];
                float gg = pr.gbufE[b*G4 + 128 + d]  + pr.bsum[128 + d];
                float go = pr.gbufE[b*G4 + 192 + d]  + pr.bsum[192 + d];
                float tcp = pr.tcb[b*TDIM + d];
                float tce = sigm(gf)*tcp + sigm(gi)*tanhf(gg);
                float the = sigm(go)*tanhf(tce);
                thl[row][d] = the; tcl[row][d] = tce;
            }
            __syncthreads();
            // odd matvec: th_even @ Whh^T
            {
                int j = tid;
                float s[4] = {0.f,0.f,0.f,0.f};
                #pragma unroll
                for (int k = 0; k < 64; k += 4) {
                    float4 wv = *(const float4*)&pr.Whh[j*TDIM + k];
                    #pragma unroll
                    for (int rr = 0; rr < 4; ++rr) {
                        float4 t4 = *(const float4*)&thl[rr][k];
                        s[rr] += t4.x*wv.x + t4.y*wv.y + t4.z*wv.z + t4.w*wv.w;
                    }
                }
                float bs = pr.bsum[j];
                #pragma unroll
                for (int rr = 0; rr < 4; ++rr)
                    gel[rr][j] = pr.gbufO[(r0+rr)*G4 + j] + bs + s[rr];
            }
            __syncthreads();
            // tracking LSTM odd
            {
                float gi = gel[row][d], gf = gel[row][64+d], gg = gel[row][128+d], go = gel[row][192+d];
                float tco = sigm(gf)*tcl[row][d] + sigm(gi)*tanhf(gg);
                float tho = sigm(go)*tanhf(tco);
                pr.tcb[b*TDIM + d] = tco;
                ush h = f2bf(tho);
                pr.thH[b*TDIM + d] = h; pr.thL[b*TDIM + d] = f2bf(tho - bf2f(h));
                __syncthreads();
                thl[row][d] = tho;
            }
            __syncthreads();
            // tree gates: g5 = P + Uhb + th_odd @ Wc^T
            for (int c = tid; c < G5; c += 256) {
                float s[4] = {0.f,0.f,0.f,0.f};
                #pragma unroll
                for (int k = 0; k < 64; k += 4) {
                    float4 wv = *(const float4*)&pr.Wc[c*TDIM + k];
                    #pragma unroll
                    for (int rr = 0; rr < 4; ++rr) {
                        float4 t4 = *(const float4*)&thl[rr][k];
                        s[rr] += t4.x*wv.x + t4.y*wv.y + t4.z*wv.z + t4.w*wv.w;
                    }
                }
                float ub = pr.Uhb[c];
                #pragma unroll
                for (int rr = 0; rr < 4; ++rr)
                    g5l[rr][c] = pr.Pbuf[(r0+rr)*G5 + c] + ub + s[rr];
            }
            __syncthreads();
            // tree-LSTM elementwise + acc update
            for (int idx = tid; idx < 4*HH; idx += 256) {
                int rr = idx / HH, c = idx - rr*HH;
                int bb = r0 + rr;
                bool left = (pr.trans[bb*TT + 2*p + 1] == 2);
                float ch = left ? pr.seq[bb*SEQB + p*600 + HH + c] : pr.acc_c[bb*HH + c];
                float gi = g5l[rr][c], go = g5l[rr][HH+c], gfh = g5l[rr][2*HH+c], gfc = g5l[rr][3*HH+c], gu = g5l[rr][4*HH+c];
                float cj = sigm(gi)*tanhf(gu) + (sigm(gfh) + sigm(gfc))*ch;
                float hj = sigm(go)*tanhf(cj);
                pr.acc_c[bb*HH + c] = cj;
                pr.acc_h[bb*HH + c] = hj;
                ush h = f2bf(hj);
                pr.accH[bb*KP + c] = h; pr.accL[bb*KP + c] = f2bf(hj - bf2f(h));
            }
        }
        btgt += NBLK;
        gbar(pr.bar, btgt);
    }
}

// ---------------- output ----------------
__global__ void k_out(const float* __restrict__ acc_h, float* __restrict__ out)
{
    int i = blockIdx.x*blockDim.x + threadIdx.x;
    if (i < BB*HH) out[i] = acc_h[i];
}

extern "C" void kernel_launch(void* const* d_in, const int* in_sizes, int n_in,
                              void* d_out, int out_size, void* d_ws, size_t ws_size,
                              hipStream_t stream)
{
    const float* seq  = (const float*)d_in[0];
    const int*   trans= (const int*)d_in[1];
    const float* Wc   = (const float*)d_in[2];
    const float* Uhw  = (const float*)d_in[3];
    const float* Uhb  = (const float*)d_in[4];
    const float* Ulw  = (const float*)d_in[5];
    const float* Urw  = (const float*)d_in[6];
    const float* Wih  = (const float*)d_in[7];
    const float* Whh  = (const float*)d_in[8];
    const float* bih  = (const float*)d_in[9];
    const float* bhh  = (const float*)d_in[10];
    const float* th0  = (const float*)d_in[11];
    const float* tc0  = (const float*)d_in[12];
    float* out = (float*)d_out;

    char* w = (char*)d_ws;
    size_t off = 0;
    auto alloc = [&](size_t nbytes) {
        void* ptr = w + off;
        off = (off + nbytes + 255) & ~(size_t)255;
        return ptr;
    };
    ush* tokH = (ush*)alloc((size_t)BB*LSEQ*KP*2);
    ush* tokL = (ush*)alloc((size_t)BB*LSEQ*KP*2);
    ush* accH = (ush*)alloc((size_t)BB*KP*2);
    ush* accL = (ush*)alloc((size_t)BB*KP*2);
    ush* ULh  = (ush*)alloc((size_t)G5*KP*2);
    ush* ULl  = (ush*)alloc((size_t)G5*KP*2);
    ush* URh  = (ush*)alloc((size_t)G5*KP*2);
    ush* URl  = (ush*)alloc((size_t)G5*KP*2);
    ush* WihH = (ush*)alloc((size_t)G4*3*KP*2);
    ush* WihL = (ush*)alloc((size_t)G4*3*KP*2);
    ush* WhhH = (ush*)alloc((size_t)G4*TDIM*2);
    ush* WhhL = (ush*)alloc((size_t)G4*TDIM*2);
    ush* thH  = (ush*)alloc((size_t)BB*TDIM*2);
    ush* thL  = (ush*)alloc((size_t)BB*TDIM*2);
    float* bsum  = (float*)alloc((size_t)G4*4);
    float* gbufE = (float*)alloc((size_t)BB*G4*4);
    float* gbufO = (float*)alloc((size_t)BB*G4*4);
    float* Pbuf  = (float*)alloc((size_t)BB*G5*4);
    float* tcb   = (float*)alloc((size_t)BB*TDIM*4);
    float* acc_c = (float*)alloc((size_t)BB*HH*4);
    float* acc_h = (float*)alloc((size_t)BB*HH*4);
    int* perm  = (int*)alloc((size_t)NP*448*4);
    int* rbarr = (int*)alloc((size_t)NP*4);
    int* bar   = (int*)alloc((size_t)256);

    k_wprep<<<960, 256, 0, stream>>>(Uhw, Ulw, Urw, Wih, Whh, bih, bhh,
                                     ULh, ULl, URh, URl, WihH, WihL, WhhH, WhhL, bsum);
    k_cvt<<<2048, 256, 0, stream>>>(seq, tokH, tokL);
    k_init<<<512, 256, 0, stream>>>(seq, th0, tc0, tokH, tokL,
                                    accH, accL, acc_c, acc_h, thH, thL, tcb);
    k_prep2<<<NP, 448, 0, stream>>>(trans, perm, rbarr, bar);

    Prm prm;
    prm.seq = seq; prm.trans = trans;
    prm.Wc = Wc; prm.Uhb = Uhb; prm.bsum = bsum;
    prm.tokH = tokH; prm.tokL = tokL;
    prm.accH = accH; prm.accL = accL;
    prm.thH = thH; prm.thL = thL;
    prm.tcb = tcb; prm.acc_c = acc_c; prm.acc_h = acc_h;
    prm.ULh = ULh; prm.ULl = ULl; prm.URh = URh; prm.URl = URl;
    prm.WihH = WihH; prm.WihL = WihL; prm.WhhH = WhhH; prm.WhhL = WhhL;
    prm.Whh = Whh;
    prm.perm = perm; prm.rbarr = rbarr;
    prm.gbufE = gbufE; prm.gbufO = gbufO; prm.Pbuf = Pbuf;
    prm.bar = bar;

    k_persist<<<NBLK, 256, 0, stream>>>(prm);

    k_out<<<(BB*HH + 255)/256, 256, 0, stream>>>(acc_h, out);
}

// Round 11
// 5591.228 us; speedup vs baseline: 1.8547x; 1.8547x over previous
//
#include <hip/hip_runtime.h>
#include <stdint.h>

#define BB 384
#define LSEQ 64
#define HH 300
#define TDIM 64
#define TT 126
#define NP 63          // pairs
#define KP 320         // padded K per 300-part
#define G4 256
#define G5 1500
#define SEQB 38400     // LSEQ*2*HH
#define NBLK 216       // persistent grid size (must all be co-resident)

typedef unsigned int u32;
typedef unsigned short ush;
typedef float f32x4 __attribute__((ext_vector_type(4)));
typedef short bf16x8 __attribute__((ext_vector_type(8)));

__device__ __forceinline__ float sigm(float x){ return 1.0f/(1.0f + expf(-x)); }
__device__ __forceinline__ ush f2bf(float x){ u32 u = __float_as_uint(x); u32 r = u + 0x7fff + ((u>>16)&1); return (ush)(r>>16); }
__device__ __forceinline__ float bf2f(ush h){ return __uint_as_float(((u32)h)<<16); }
__device__ __forceinline__ bf16x8 ld16(const ush* p){ return *reinterpret_cast<const bf16x8*>(p); }
__device__ __forceinline__ void mfma16(f32x4& d, bf16x8 a, bf16x8 b){
    d = __builtin_amdgcn_mfma_f32_16x16x32_bf16(a, b, d, 0, 0, 0);
}

// grid barrier v2: ONE release fence, POSTED relaxed add (result discarded ->
// fire-and-forget global_atomic_add, no per-add L2 writeback), RELAXED polls
// (r9's ACQUIRE-per-poll emitted a cache invalidate per iteration = 81 us/barrier),
// ONE acquire fence on exit.
__device__ __forceinline__ void gbar(int* cnt, int target) {
    __syncthreads();
    if (threadIdx.x == 0) {
        __threadfence();   // release: publish my writes once
        __hip_atomic_fetch_add(cnt, 1, __ATOMIC_RELAXED, __HIP_MEMORY_SCOPE_AGENT);
        while (__hip_atomic_load(cnt, __ATOMIC_RELAXED, __HIP_MEMORY_SCOPE_AGENT) < target)
            __builtin_amdgcn_s_sleep(4);
        __threadfence();   // acquire: invalidate stale lines once
    }
    __syncthreads();
}

// ---------------- weight prep: bf16 hi/lo planes, K padded 300->320; WcT transpose ----------------
__global__ void k_wprep(const float* __restrict__ Uh, const float* __restrict__ Ul,
                        const float* __restrict__ Ur, const float* __restrict__ Wih,
                        const float* __restrict__ Whh, const float* __restrict__ Wc,
                        const float* __restrict__ bih, const float* __restrict__ bhh,
                        ush* ULh, ush* ULl, ush* URh, ush* URl,
                        ush* WihH, ush* WihL, ush* WhhH, ush* WhhL,
                        float* WcT, float* bsum)
{
    int i0 = blockIdx.x*blockDim.x + threadIdx.x;
    int stride = gridDim.x*blockDim.x;
    for (int i = i0; i < G5*KP; i += stride) {
        int j = i / KP, k = i - j*KP;
        float vl = 0.f, vr = 0.f;
        if (k < HH) { float u = Uh[j*HH+k]; vl = u + Ul[j*HH+k]; vr = u + Ur[j*HH+k]; }
        ush h;
        h = f2bf(vl); ULh[i] = h; ULl[i] = f2bf(vl - bf2f(h));
        h = f2bf(vr); URh[i] = h; URl[i] = f2bf(vr - bf2f(h));
    }
    for (int i = i0; i < G4*3*KP; i += stride) {
        int j = i / (3*KP), kk = i - j*(3*KP);
        int part = kk / KP, k = kk - part*KP;
        float v = (k < HH) ? Wih[j*900 + part*HH + k] : 0.f;
        ush h = f2bf(v); WihH[i] = h; WihL[i] = f2bf(v - bf2f(h));
    }
    for (int i = i0; i < G4*TDIM; i += stride) {
        float v = Whh[i]; ush h = f2bf(v); WhhH[i] = h; WhhL[i] = f2bf(v - bf2f(h));
    }
    for (int i = i0; i < G5*TDIM; i += stride) {
        int c = i / TDIM, k = i - c*TDIM;
        WcT[k*G5 + c] = Wc[i];            // [k][c] layout for coalesced B-phase reads
    }
    for (int i = i0; i < G4; i += stride) bsum[i] = bih[i] + bhh[i];
}

// ---------------- token h-part -> bf16 hi/lo, [b*64+t][320] ----------------
__global__ void k_cvt(const float* __restrict__ seq, ush* tokH, ush* tokL)
{
    int i0 = blockIdx.x*blockDim.x + threadIdx.x;
    int stride = gridDim.x*blockDim.x;
    for (int i = i0; i < BB*LSEQ*KP; i += stride) {
        int bt = i / KP, k = i - bt*KP;
        int b = bt >> 6, t = bt & 63;
        float v = (k < HH) ? seq[b*SEQB + t*600 + k] : 0.f;
        ush h = f2bf(v); tokH[i] = h; tokL[i] = f2bf(v - bf2f(h));
    }
}

// ---------------- init state ----------------
__global__ void k_init(const float* __restrict__ seq, const float* __restrict__ th0,
                       const float* __restrict__ tc0, const ush* __restrict__ tokH,
                       const ush* __restrict__ tokL,
                       ush* accH, ush* accL, float* acc_c, float* acc_h,
                       ush* thH, ush* thL, float* tc_buf)
{
    int i0 = blockIdx.x*blockDim.x + threadIdx.x;
    int stride = gridDim.x*blockDim.x;
    for (int i = i0; i < BB*KP; i += stride) {          // acc = token0
        int b = i / KP, k = i - b*KP;
        accH[i] = tokH[b*LSEQ*KP + k]; accL[i] = tokL[b*LSEQ*KP + k];
    }
    for (int i = i0; i < BB*HH; i += stride) {
        int b = i / HH, c = i - b*HH;
        acc_c[i] = seq[b*SEQB + HH + c];
        acc_h[i] = seq[b*SEQB + c];
    }
    for (int i = i0; i < BB*TDIM; i += stride) {
        float v = th0[i]; ush h = f2bf(v);
        thH[i] = h; thL[i] = f2bf(v - bf2f(h));
        tc_buf[i] = tc0[i];
    }
}

// ---------------- per-pair left/right permutation (+ zero barrier counter) ----------------
__global__ __launch_bounds__(448) void k_prep2(const int* __restrict__ trans, int* perm, int* rbarr,
                                               int* bar)
{
    int p = blockIdx.x, t = threadIdx.x;
    if (p == 0 && t == 0) *bar = 0;
    __shared__ int cl, cr, rb;
    if (t == 0) { cl = 0; cr = 0; }
    __syncthreads();
    int isleft = 0;
    if (t < BB) {
        isleft = (trans[t*TT + 2*p + 1] == 2);
        if (isleft) atomicAdd(&cl, 1); else atomicAdd(&cr, 1);
    }
    __syncthreads();
    if (t == 0) { rb = ((cl + 63) >> 6) << 6; rbarr[p] = rb; cl = 0; cr = 0; }
    __syncthreads();
    perm[p*448 + t] = -1;
    __syncthreads();
    if (t < BB) {
        int slot = isleft ? atomicAdd(&cl, 1) : rb + atomicAdd(&cr, 1);
        perm[p*448 + slot] = t;
    }
}

// ---------------- persistent kernel: all 63 pairs, hand-rolled grid barrier ----------------
struct Prm {
    const float* seq; const int* trans;
    const float* WcT; const float* Uhb; const float* bsum;
    const ush* tokH; const ush* tokL;
    ush* accH; ush* accL;
    ush* thH; ush* thL;
    float* tcb; float* acc_c; float* acc_h;
    const ush* ULh; const ush* ULl; const ush* URh; const ush* URl;
    const ush* WihH; const ush* WihL; const ush* WhhH; const ush* WhhL;
    const float* Whh;
    const int* perm; const int* rbarr;
    float* gbufE; float* gbufO; float* Pbuf;
    int* bar;
};

__global__ __launch_bounds__(256) void k_persist(Prm pr)
{
    const int bid = blockIdx.x, tid = threadIdx.x;
    const int w = tid >> 6, lane = tid & 63;
    const int l15 = lane & 15, kg = lane >> 4;

    __shared__ __align__(16) float thl[4][64], tcl[4][64], gel[4][256];
    __shared__ __align__(16) float g5l[4][G5];

    int btgt = 0;
    for (int p = 0; p < NP; ++p) {
        // ================= A phase: MFMA GEMMs =================
        if (bid < 48) {
            // GA_even / GA_odd tiles (fixed block->tile mapping for L2 weight residency)
            const int seg = (bid >= 24);
            const int q = bid - seg*24;
            const int rt = q >> 2, ct = q & 3;
            const int r0 = rt*64, c0 = ct*64;
            const int b = r0 + w*16 + l15;
            f32x4 acc[4];
            #pragma unroll
            for (int cf = 0; cf < 4; ++cf) acc[cf] = (f32x4){0.f,0.f,0.f,0.f};
            const ush* aH[3]; const ush* aL[3];
            if (!seg) {
                aH[0] = pr.tokH + (b*64 + p)*KP;   aL[0] = pr.tokL + (b*64 + p)*KP;
                aH[1] = pr.accH + b*KP;            aL[1] = pr.accL + b*KP;
                aH[2] = pr.tokH + (b*64)*KP;       aL[2] = pr.tokL + (b*64)*KP;
            } else {
                aH[0] = pr.tokH + (b*64 + p+1)*KP; aL[0] = pr.tokL + (b*64 + p+1)*KP;
                aH[1] = pr.tokH + (b*64 + p)*KP;   aL[1] = pr.tokL + (b*64 + p)*KP;
                aH[2] = pr.accH + b*KP;            aL[2] = pr.accL + b*KP;
            }
            const ush* bH[4]; const ush* bL[4];
            #pragma unroll
            for (int cf = 0; cf < 4; ++cf) {
                int j = c0 + cf*16 + l15;
                bH[cf] = pr.WihH + j*(3*KP) + kg*8;
                bL[cf] = pr.WihL + j*(3*KP) + kg*8;
            }
            #pragma unroll
            for (int part = 0; part < 3; ++part) {
                const ush* pah = aH[part] + kg*8;
                const ush* pal = aL[part] + kg*8;
                const int ko = part*KP;
                #pragma unroll
                for (int kc = 0; kc < KP; kc += 32) {
                    bf16x8 ah = ld16(pah + kc);
                    bf16x8 al = ld16(pal + kc);
                    bf16x8 b0 = ld16(bH[0]+ko+kc), b1 = ld16(bH[1]+ko+kc), b2 = ld16(bH[2]+ko+kc), b3 = ld16(bH[3]+ko+kc);
                    bf16x8 c0v = ld16(bL[0]+ko+kc), c1 = ld16(bL[1]+ko+kc), c2 = ld16(bL[2]+ko+kc), c3 = ld16(bL[3]+ko+kc);
                    mfma16(acc[0],ah,b0); mfma16(acc[1],ah,b1); mfma16(acc[2],ah,b2); mfma16(acc[3],ah,b3);
                    mfma16(acc[0],al,b0); mfma16(acc[1],al,b1); mfma16(acc[2],al,b2); mfma16(acc[3],al,b3);
                    mfma16(acc[0],ah,c0v); mfma16(acc[1],ah,c1); mfma16(acc[2],ah,c2); mfma16(acc[3],ah,c3);
                }
            }
            if (!seg) {  // + th_prev @ Whh^T, K=64
                const ush* pah = pr.thH + b*TDIM + kg*8;
                const ush* pal = pr.thL + b*TDIM + kg*8;
                #pragma unroll
                for (int kc = 0; kc < 64; kc += 32) {
                    bf16x8 ah = ld16(pah + kc);
                    bf16x8 al = ld16(pal + kc);
                    #pragma unroll
                    for (int cf = 0; cf < 4; ++cf) {
                        int j = c0 + cf*16 + l15;
                        bf16x8 bh = ld16(pr.WhhH + j*TDIM + kg*8 + kc);
                        bf16x8 bl = ld16(pr.WhhL + j*TDIM + kg*8 + kc);
                        mfma16(acc[cf], ah, bh);
                        mfma16(acc[cf], al, bh);
                        mfma16(acc[cf], ah, bl);
                    }
                }
            }
            float* out = seg ? pr.gbufO : pr.gbufE;
            #pragma unroll
            for (int r = 0; r < 4; ++r) {
                int row = r0 + w*16 + kg*4 + r;
                #pragma unroll
                for (int cf = 0; cf < 4; ++cf) {
                    int col = c0 + cf*16 + l15;
                    out[row*G4 + col] = acc[cf][r];
                }
            }
        } else {
            // P tiles (bid 48..215)
            const int q = bid - 48;
            const int rt = q / 24, ct = q - rt*24;
            const int s0 = rt*64, c0 = ct*64;
            const int* pp = pr.perm + p*448;
            if (pp[s0] >= 0) {
                const int RB = pr.rbarr[p];
                const bool left = (s0 < RB);
                f32x4 acc[4];
                #pragma unroll
                for (int cf = 0; cf < 4; ++cf) acc[cf] = (f32x4){0.f,0.f,0.f,0.f};
                int ar = pp[s0 + w*16 + l15]; if (ar < 0) ar = 0;
                const ush* pah = (left ? pr.tokH + (ar*64 + p)*KP : pr.accH + ar*KP) + kg*8;
                const ush* pal = (left ? pr.tokL + (ar*64 + p)*KP : pr.accL + ar*KP) + kg*8;
                const ush* WBh = left ? pr.ULh : pr.URh;
                const ush* WBl = left ? pr.ULl : pr.URl;
                const ush* bH[4]; const ush* bL[4];
                #pragma unroll
                for (int cf = 0; cf < 4; ++cf) {
                    int j = c0 + cf*16 + l15; if (j > G5-1) j = G5-1;
                    bH[cf] = WBh + j*KP + kg*8;
                    bL[cf] = WBl + j*KP + kg*8;
                }
                #pragma unroll
                for (int kc = 0; kc < KP; kc += 32) {
                    bf16x8 ah = ld16(pah + kc);
                    bf16x8 al = ld16(pal + kc);
                    bf16x8 b0 = ld16(bH[0]+kc), b1 = ld16(bH[1]+kc), b2 = ld16(bH[2]+kc), b3 = ld16(bH[3]+kc);
                    bf16x8 c0v = ld16(bL[0]+kc), c1 = ld16(bL[1]+kc), c2 = ld16(bL[2]+kc), c3 = ld16(bL[3]+kc);
                    mfma16(acc[0],ah,b0); mfma16(acc[1],ah,b1); mfma16(acc[2],ah,b2); mfma16(acc[3],ah,b3);
                    mfma16(acc[0],al,b0); mfma16(acc[1],al,b1); mfma16(acc[2],al,b2); mfma16(acc[3],al,b3);
                    mfma16(acc[0],ah,c0v); mfma16(acc[1],ah,c1); mfma16(acc[2],ah,c2); mfma16(acc[3],ah,c3);
                }
                #pragma unroll
                for (int r = 0; r < 4; ++r) {
                    int prw = pp[s0 + w*16 + kg*4 + r];
                    if (prw < 0) continue;
                    #pragma unroll
                    for (int cf = 0; cf < 4; ++cf) {
                        int col = c0 + cf*16 + l15;
                        if (col < G5) pr.Pbuf[prw*G5 + col] = acc[cf][r];
                    }
                }
            }
        }
        btgt += NBLK;
        gbar(pr.bar, btgt);

        // ================= B phase: sequential core =================
        if (bid < 96) {
            const int r0 = bid*4;
            const int row = tid >> 6, d = tid & 63;
            const int b = r0 + row;
            // tracking LSTM even
            {
                float gi = pr.gbufE[b*G4 + d]        + pr.bsum[d];
                float gf = pr.gbufE[b*G4 + 64 + d]   + pr.bsum[64 + d];
                float gg = pr.gbufE[b*G4 + 128 + d]  + pr.bsum[128 + d];
                float go = pr.gbufE[b*G4 + 192 + d]  + pr.bsum[192 + d];
                float tcp = pr.tcb[b*TDIM + d];
                float tce = sigm(gf)*tcp + sigm(gi)*tanhf(gg);
                float the = sigm(go)*tanhf(tce);
                thl[row][d] = the; tcl[row][d] = tce;
            }
            __syncthreads();
            // odd matvec: th_even @ Whh^T
            {
                int j = tid;
                float s[4] = {0.f,0.f,0.f,0.f};
                #pragma unroll
                for (int k = 0; k < 64; k += 4) {
                    float4 wv = *(const float4*)&pr.Whh[j*TDIM + k];
                    #pragma unroll
                    for (int rr = 0; rr < 4; ++rr) {
                        float4 t4 = *(const float4*)&thl[rr][k];
                        s[rr] += t4.x*wv.x + t4.y*wv.y + t4.z*wv.z + t4.w*wv.w;
                    }
                }
                float bs = pr.bsum[j];
                #pragma unroll
                for (int rr = 0; rr < 4; ++rr)
                    gel[rr][j] = pr.gbufO[(r0+rr)*G4 + j] + bs + s[rr];
            }
            __syncthreads();
            // tracking LSTM odd
            {
                float gi = gel[row][d], gf = gel[row][64+d], gg = gel[row][128+d], go = gel[row][192+d];
                float tco = sigm(gf)*tcl[row][d] + sigm(gi)*tanhf(gg);
                float tho = sigm(go)*tanhf(tco);
                pr.tcb[b*TDIM + d] = tco;
                ush h = f2bf(tho);
                pr.thH[b*TDIM + d] = h; pr.thL[b*TDIM + d] = f2bf(tho - bf2f(h));
                __syncthreads();
                thl[row][d] = tho;
            }
            __syncthreads();
            // tree gates: g5 = P + Uhb + th_odd @ WcT (k-major, coalesced)
            for (int c = tid; c < G5; c += 256) {
                float s[4] = {0.f,0.f,0.f,0.f};
                #pragma unroll 16
                for (int k = 0; k < 64; ++k) {
                    float wv = pr.WcT[k*G5 + c];
                    #pragma unroll
                    for (int rr = 0; rr < 4; ++rr)
                        s[rr] += thl[rr][k] * wv;
                }
                float ub = pr.Uhb[c];
                #pragma unroll
                for (int rr = 0; rr < 4; ++rr)
                    g5l[rr][c] = pr.Pbuf[(r0+rr)*G5 + c] + ub + s[rr];
            }
            __syncthreads();
            // tree-LSTM elementwise + acc update
            for (int idx = tid; idx < 4*HH; idx += 256) {
                int rr = idx / HH, c = idx - rr*HH;
                int bb = r0 + rr;
                bool left = (pr.trans[bb*TT + 2*p + 1] == 2);
                float ch = left ? pr.seq[bb*SEQB + p*600 + HH + c] : pr.acc_c[bb*HH + c];
                float gi = g5l[rr][c], go = g5l[rr][HH+c], gfh = g5l[rr][2*HH+c], gfc = g5l[rr][3*HH+c], gu = g5l[rr][4*HH+c];
                float cj = sigm(gi)*tanhf(gu) + (sigm(gfh) + sigm(gfc))*ch;
                float hj = sigm(go)*tanhf(cj);
                pr.acc_c[bb*HH + c] = cj;
                pr.acc_h[bb*HH + c] = hj;
                ush h = f2bf(hj);
                pr.accH[bb*KP + c] = h; pr.accL[bb*KP + c] = f2bf(hj - bf2f(h));
            }
        }
        btgt += NBLK;
        gbar(pr.bar, btgt);
    }
}

// ---------------- output ----------------
__global__ void k_out(const float* __restrict__ acc_h, float* __restrict__ out)
{
    int i = blockIdx.x*blockDim.x + threadIdx.x;
    if (i < BB*HH) out[i] = acc_h[i];
}

extern "C" void kernel_launch(void* const* d_in, const int* in_sizes, int n_in,
                              void* d_out, int out_size, void* d_ws, size_t ws_size,
                              hipStream_t stream)
{
    const float* seq  = (const float*)d_in[0];
    const int*   trans= (const int*)d_in[1];
    const float* Wc   = (const float*)d_in[2];
    const float* Uhw  = (const float*)d_in[3];
    const float* Uhb  = (const float*)d_in[4];
    const float* Ulw  = (const float*)d_in[5];
    const float* Urw  = (const float*)d_in[6];
    const float* Wih  = (const float*)d_in[7];
    const float* Whh  = (const float*)d_in[8];
    const float* bih  = (const float*)d_in[9];
    const float* bhh  = (const float*)d_in[10];
    const float* th0  = (const float*)d_in[11];
    const float* tc0  = (const float*)d_in[12];
    float* out = (float*)d_out;

    char* w = (char*)d_ws;
    size_t off = 0;
    auto alloc = [&](size_t nbytes) {
        void* ptr = w + off;
        off = (off + nbytes + 255) & ~(size_t)255;
        return ptr;
    };
    ush* tokH = (ush*)alloc((size_t)BB*LSEQ*KP*2);
    ush* tokL = (ush*)alloc((size_t)BB*LSEQ*KP*2);
    ush* accH = (ush*)alloc((size_t)BB*KP*2);
    ush* accL = (ush*)alloc((size_t)BB*KP*2);
    ush* ULh  = (ush*)alloc((size_t)G5*KP*2);
    ush* ULl  = (ush*)alloc((size_t)G5*KP*2);
    ush* URh  = (ush*)alloc((size_t)G5*KP*2);
    ush* URl  = (ush*)alloc((size_t)G5*KP*2);
    ush* WihH = (ush*)alloc((size_t)G4*3*KP*2);
    ush* WihL = (ush*)alloc((size_t)G4*3*KP*2);
    ush* WhhH = (ush*)alloc((size_t)G4*TDIM*2);
    ush* WhhL = (ush*)alloc((size_t)G4*TDIM*2);
    ush* thH  = (ush*)alloc((size_t)BB*TDIM*2);
    ush* thL  = (ush*)alloc((size_t)BB*TDIM*2);
    float* WcT   = (float*)alloc((size_t)G5*TDIM*4);
    float* bsum  = (float*)alloc((size_t)G4*4);
    float* gbufE = (float*)alloc((size_t)BB*G4*4);
    float* gbufO = (float*)alloc((size_t)BB*G4*4);
    float* Pbuf  = (float*)alloc((size_t)BB*G5*4);
    float* tcb   = (float*)alloc((size_t)BB*TDIM*4);
    float* acc_c = (float*)alloc((size_t)BB*HH*4);
    float* acc_h = (float*)alloc((size_t)BB*HH*4);
    int* perm  = (int*)alloc((size_t)NP*448*4);
    int* rbarr = (int*)alloc((size_t)NP*4);
    int* bar   = (int*)alloc((size_t)256);

    k_wprep<<<960, 256, 0, stream>>>(Uhw, Ulw, Urw, Wih, Whh, Wc, bih, bhh,
                                     ULh, ULl, URh, URl, WihH, WihL, WhhH, WhhL, WcT, bsum);
    k_cvt<<<2048, 256, 0, stream>>>(seq, tokH, tokL);
    k_init<<<512, 256, 0, stream>>>(seq, th0, tc0, tokH, tokL,
                                    accH, accL, acc_c, acc_h, thH, thL, tcb);
    k_prep2<<<NP, 448, 0, stream>>>(trans, perm, rbarr, bar);

    Prm prm;
    prm.seq = seq; prm.trans = trans;
    prm.WcT = WcT; prm.Uhb = Uhb; prm.bsum = bsum;
    prm.tokH = tokH; prm.tokL = tokL;
    prm.accH = accH; prm.accL = accL;
    prm.thH = thH; prm.thL = thL;
    prm.tcb = tcb; prm.acc_c = acc_c; prm.acc_h = acc_h;
    prm.ULh = ULh; prm.ULl = ULl; prm.URh = URh; prm.URl = URl;
    prm.WihH = WihH; prm.WihL = WihL; prm.WhhH = WhhH; prm.WhhL = WhhL;
    prm.Whh = Whh;
    prm.perm = perm; prm.rbarr = rbarr;
    prm.gbufE = gbufE; prm.gbufO = gbufO; prm.Pbuf = Pbuf;
    prm.bar = bar;

    k_persist<<<NBLK, 256, 0, stream>>>(prm);

    k_out<<<(BB*HH + 255)/256, 256, 0, stream>>>(acc_h, out);
}